// Round 4
// baseline (315.016 us; speedup 1.0000x reference)
//
#include <hip/hip_runtime.h>
#include <hip/hip_bf16.h>

#define B_    8
#define CIN   64
#define COUT  64
#define RN_   4
#define H_    128
#define W_    128
#define HW_   (H_ * W_)
#define BN_EPS 1e-5f

typedef short v8s __attribute__((ext_vector_type(8)));
typedef float v4f __attribute__((ext_vector_type(4)));

__device__ __forceinline__ unsigned short f2bf(float f) {
    unsigned int u = __float_as_uint(f);
    u += 0x7FFFu + ((u >> 16) & 1u);       // round-to-nearest-even
    return (unsigned short)(u >> 16);
}

// ---------------------------------------------------------------------------
// prep: merged transpose kernels (one launch)
//   blocks [0,1024):    x fp32 [b][c][h][w] -> xT bf16 [b][h][w][c]
//   blocks [1024,1152): kernel fp32 -> kT bf16 in MFMA A-fragment order
//   block  1152:        mask weights fp32 [r][c][t] -> mwT bf16 in A-frag
//                       order (region replicated to rows r, r+4, r+8, r+12)
// ---------------------------------------------------------------------------
__global__ __launch_bounds__(256) void prep(const float* __restrict__ x,
                                            const float* __restrict__ kr,
                                            const float* __restrict__ mw,
                                            unsigned short* __restrict__ xT,
                                            unsigned short* __restrict__ kT,
                                            unsigned short* __restrict__ mwT) {
    __shared__ float sl[16 * 64 * 9];                 // 36 KB (union of both uses)
    if (blockIdx.x < 1024) {
        const int b = blockIdx.x >> 7, h = blockIdx.x & 127;
        const float* xp = x + (size_t)b * CIN * HW_ + (size_t)h * W_;
        for (int idx = threadIdx.x; idx < CIN * (W_ / 4); idx += 256) {
            const int c = idx >> 5, w4 = (idx & 31) << 2;   // float4 loads (G13)
            const float4 v = *(const float4*)(xp + (size_t)c * HW_ + w4);
            float* s = &sl[c * 129 + w4];                   // 129-pad: conflict-free col reads
            s[0] = v.x; s[1] = v.y; s[2] = v.z; s[3] = v.w;
        }
        __syncthreads();
        unsigned short* op = xT + ((size_t)b * H_ + h) * (W_ * CIN);
        for (int idx = threadIdx.x; idx < (W_ * CIN) / 8; idx += 256) {
            const int w = idx >> 3, c0 = (idx & 7) << 3;
            int4 v;
            v.x = f2bf(sl[(c0 + 0) * 129 + w]) | ((unsigned)f2bf(sl[(c0 + 1) * 129 + w]) << 16);
            v.y = f2bf(sl[(c0 + 2) * 129 + w]) | ((unsigned)f2bf(sl[(c0 + 3) * 129 + w]) << 16);
            v.z = f2bf(sl[(c0 + 4) * 129 + w]) | ((unsigned)f2bf(sl[(c0 + 5) * 129 + w]) << 16);
            v.w = f2bf(sl[(c0 + 6) * 129 + w]) | ((unsigned)f2bf(sl[(c0 + 7) * 129 + w]) << 16);
            *(int4*)(op + (w << 6) + c0) = v;
        }
    } else if (blockIdx.x < 1152) {
        const int bid = blockIdx.x - 1024;
        const int br = bid >> 2, oq = bid & 3;        // br = b*4+r; oq = 16-o chunk
        const float* src = kr + ((size_t)br * 64 + oq * 16) * (64 * 9);
        for (int idx = threadIdx.x; idx < 2304; idx += 256)
            *(float4*)&sl[idx << 2] = *(const float4*)&src[idx << 2];
        __syncthreads();
        unsigned short* dst = kT + (size_t)br * (9 * 4096);
        for (int idx = threadIdx.x; idx < 1152; idx += 256) {
            const int t = idx >> 7, rem = idx & 127, o16 = rem >> 3, c8 = (rem & 7) << 3;
            unsigned short s[8];
            #pragma unroll
            for (int j = 0; j < 8; j++)
                s[j] = f2bf(sl[(o16 * 64 + c8 + j) * 9 + t]);
            int4 v;
            v.x = s[0] | ((unsigned)s[1] << 16);
            v.y = s[2] | ((unsigned)s[3] << 16);
            v.z = s[4] | ((unsigned)s[5] << 16);
            v.w = s[6] | ((unsigned)s[7] << 16);
            // fragment order: o = oq*16+o16 -> fm=oq, i=o16 ; c = c8+j -> ks=c8>>5, g=(c8>>3)&3
            const int q  = oq * 2 + (c8 >> 5);        // frag index fm*2+ks
            const int gg = (c8 >> 3) & 3;             // g
            *(int4*)(dst + (size_t)t * 4096 + q * 512 + (gg * 16 + o16) * 8) = v;
        }
    } else {
        // mwT[tile=tap*2+ks][lane][8]: lane=(g<<4)|i, row i holds region i&3
        for (int idx = threadIdx.x; idx < 9 * 2 * 64 * 8; idx += 256) {
            const int tile = idx >> 9;                // tap*2+ks
            const int tap = tile >> 1, ks = tile & 1;
            const int lane = (idx >> 3) & 63, j = idx & 7;
            const int g = lane >> 4, r = lane & 3;    // region = i&3
            const int c = ks * 32 + g * 8 + j;
            mwT[idx] = f2bf(mw[(r * 64 + c) * 9 + tap]);
        }
    }
}

// ---------------------------------------------------------------------------
// fused: dynamic grouped conv + mask conv/softmax + region sum + BN + ReLU.
// Round 4: K-split across waves. 512-thread blocks, 8 waves: waves 0-3 do
// regions 0-1 (rows 0-3), waves 4-7 do regions 2-3 (same rows). Grid stays
// 512 blocks -> 2 blocks/CU but 16 waves/CU (was 8). Per-wave structure
// (1 row x 64 cols, 4fm x 4fn, 256 B A-traffic per MFMA) identical to the
// 47.7us round-2 kernel. Partial o_acc combined via dead xs LDS at the end.
// ---------------------------------------------------------------------------
#define XS_W     66                      // 64 + 2 halo columns
#define XS_ROWS  6                       // 4 output rows + 2 halo rows
#define XS_ELEMS (XS_ROWS * XS_W * 64)   // 25344 shorts = 50.7 KB, swizzled

__global__ __launch_bounds__(512, 4) void main_conv(
        const unsigned short* __restrict__ xT,
        const unsigned short* __restrict__ kT,
        const unsigned short* __restrict__ mwT,
        const float* __restrict__ mb,
        const float* __restrict__ bn_gamma, const float* __restrict__ bn_beta,
        const float* __restrict__ bn_mean,  const float* __restrict__ bn_var,
        float* __restrict__ outp, float* __restrict__ masks_g) {
    __shared__ __align__(16) unsigned short xs[XS_ELEMS];
    __shared__ float scale_s[COUT];
    __shared__ float shift_s[COUT];

    const int tid = threadIdx.x;
    const int b  = blockIdx.z;
    const int w0 = blockIdx.y << 6;           // 0 or 64
    const int h0 = blockIdx.x << 2;           // 0..124
    const int lane = tid & 63;
    const int wv = tid >> 6;                  // 0..7
    const int wr = wv & 3;                    // output row within tile
    const int rh = wv >> 2;                   // 0: regions 0-1, 1: regions 2-3
    const int i = lane & 15, g = lane >> 4;
    const int h_out = h0 + wr;

    // ---- stage x halo tile, XOR-swizzled: slot' = slot ^ (rw&7) ----
    const unsigned short* xb = xT + (size_t)b * (HW_ * CIN);
    #pragma unroll
    for (int row = 0; row < XS_ROWS; row++) {
        const int h_in = h0 - 1 + row;
        const bool hok = (h_in >= 0) && (h_in < H_);
        for (int idx = tid; idx < XS_W * 8; idx += 512) {
            const int w = idx >> 3, c8 = (idx & 7) << 3;
            const int w_in = w0 - 1 + w;
            int4 v = make_int4(0, 0, 0, 0);
            if (hok && (w_in >= 0) && (w_in < W_))
                v = *(const int4*)(xb + ((h_in * W_ + w_in) << 6) + c8);
            const int rw = row * XS_W + w;
            *(int4*)(&xs[(rw << 6) + (((c8 >> 3) ^ (rw & 7)) << 3)]) = v;
        }
    }
    if (tid < COUT) {
        const float sc = bn_gamma[tid] * rsqrtf(bn_var[tid] + BN_EPS);
        scale_s[tid] = sc;
        shift_s[tid] = bn_beta[tid] - bn_mean[tid] * sc;
    }
    const float mb0 = mb[0], mb1 = mb[1], mb2 = mb[2], mb3 = mb[3];

    __syncthreads();                          // xs ready (K-loop is barrier-free)

    // ---- logits pre-pass: 9 taps, A = mwT from global, softmax -> masks ----
    // Both wave-halves compute the full softmax (cheap, avoids an early sync).
    v4f lg_acc[4];
    #pragma unroll
    for (int fn = 0; fn < 4; fn++) lg_acc[fn] = (v4f){0.f, 0.f, 0.f, 0.f};
    for (int tap = 0; tap < 9; tap++) {
        const int rwb = (wr + tap / 3) * XS_W + i + tap % 3;
        const int base = (rwb << 6) + ((g ^ (rwb & 7)) << 3);
        #pragma unroll
        for (int ks = 0; ks < 2; ks++) {
            const v8s am = *(const v8s*)(mwT + (((tap * 2 + ks) << 9) + (lane << 3)));
            #pragma unroll
            for (int fn = 0; fn < 4; fn++) {
                const v8s bv = *(const v8s*)(&xs[(base + (fn << 10)) ^ (ks << 5)]);
                lg_acc[fn] = __builtin_amdgcn_mfma_f32_16x16x32_bf16(am, bv, lg_acc[fn], 0, 0, 0);
            }
        }
    }
    unsigned mk0[4], mk1[4];                  // bf16-packed masks: [fn] (r0|r1), (r2|r3)
    #pragma unroll
    for (int fn = 0; fn < 4; fn++) {
        const float l0 = lg_acc[fn][0] + mb0, l1 = lg_acc[fn][1] + mb1;
        const float l2 = lg_acc[fn][2] + mb2, l3 = lg_acc[fn][3] + mb3;
        const float mx = fmaxf(fmaxf(l0, l1), fmaxf(l2, l3));
        const float e0 = __expf(l0 - mx), e1 = __expf(l1 - mx);
        const float e2 = __expf(l2 - mx), e3 = __expf(l3 - mx);
        const float inv = 1.f / (e0 + e1 + e2 + e3);
        const float m0 = e0 * inv, m1 = e1 * inv, m2 = e2 * inv, m3 = e3 * inv;
        if (rh == 0 && g == 0) {              // lanes 0..15 hold valid rows 0..3
            float* mp = masks_g + ((size_t)b * RN_ * H_ + h_out) * W_ + w0 + fn * 16 + i;
            mp[0] = m0; mp[HW_] = m1; mp[2 * HW_] = m2; mp[3 * HW_] = m3;
        }
        mk0[fn] = f2bf(m0) | ((unsigned)f2bf(m1) << 16);
        mk1[fn] = f2bf(m2) | ((unsigned)f2bf(m3) << 16);
    }

    // ---- main loop: 18 rt per wave (this half's 2 regions), reg dbuf, no barriers ----
    const unsigned short* kb = kT + (size_t)b * (36 * 4096)
                             + ((size_t)(rh * 18) << 12) + (lane << 3);
    v4f y_acc[4][4], o_acc[4][4];
    #pragma unroll
    for (int fm = 0; fm < 4; fm++)
        #pragma unroll
        for (int fn = 0; fn < 4; fn++) {
            y_acc[fm][fn] = (v4f){0.f, 0.f, 0.f, 0.f};
            o_acc[fm][fn] = (v4f){0.f, 0.f, 0.f, 0.f};
        }

    v8s aA[8], aB[8];
    #pragma unroll
    for (int q = 0; q < 8; q++)               // prologue: first tile of this half
        aA[q] = *(const v8s*)(kb + (q << 9));

    int tap = 0, r = rh * 2;
    auto step = [&](const v8s (&ac)[8]) {
        const int rwb = (wr + tap / 3) * XS_W + i + tap % 3;
        const int base = (rwb << 6) + ((g ^ (rwb & 7)) << 3);
        __builtin_amdgcn_s_setprio(1);
        #pragma unroll
        for (int ks = 0; ks < 2; ks++) {
            v8s bfr[4];
            #pragma unroll
            for (int fn = 0; fn < 4; fn++)
                bfr[fn] = *(const v8s*)(&xs[(base + (fn << 10)) ^ (ks << 5)]);
            #pragma unroll
            for (int fm = 0; fm < 4; fm++)
                #pragma unroll
                for (int fn = 0; fn < 4; fn++)
                    y_acc[fm][fn] = __builtin_amdgcn_mfma_f32_16x16x32_bf16(
                        ac[fm * 2 + ks], bfr[fn], y_acc[fm][fn], 0, 0, 0);
        }
        __builtin_amdgcn_s_setprio(0);
        if (++tap == 9) {                     // region done: fold mask weight
            tap = 0;
            #pragma unroll
            for (int fn = 0; fn < 4; fn++) {
                unsigned pk = (r & 2) ? mk1[fn] : mk0[fn];
                pk = __shfl(pk, i);           // broadcast from g==0 lane of col i
                const float mv = (r & 1) ? __uint_as_float(pk & 0xffff0000u)
                                         : __uint_as_float(pk << 16);
                #pragma unroll
                for (int fm = 0; fm < 4; fm++) {
                    o_acc[fm][fn] += mv * y_acc[fm][fn];
                    y_acc[fm][fn] = (v4f){0.f, 0.f, 0.f, 0.f};
                }
            }
            r++;
        }
    };

    for (int rt = 0; rt < 18; rt += 2) {
        const unsigned short* kn = kb + ((size_t)(rt + 1) << 12);
        #pragma unroll
        for (int q = 0; q < 8; q++)           // issue rt+1 loads before compute
            aB[q] = *(const v8s*)(kn + (q << 9));
        step(aA);
        if (rt + 2 < 18) {
            const unsigned short* kn2 = kb + ((size_t)(rt + 2) << 12);
            #pragma unroll
            for (int q = 0; q < 8; q++)
                aA[q] = *(const v8s*)(kn2 + (q << 9));
        }
        step(aB);
    }

    // ---- combine halves via dead xs LDS (2 x 32KB rounds), BN + ReLU + store ----
    __syncthreads();                          // all waves done reading xs
    v4f* cb = (v4f*)xs;
    #pragma unroll
    for (int half = 0; half < 2; half++) {
        if (rh == 1) {
            #pragma unroll
            for (int fh = 0; fh < 2; fh++)
                #pragma unroll
                for (int fn = 0; fn < 4; fn++)
                    cb[(((wr << 1) | fh) << 8) + (fn << 6) + lane] = o_acc[half * 2 + fh][fn];
        }
        __syncthreads();
        if (rh == 0) {
            #pragma unroll
            for (int fh = 0; fh < 2; fh++) {
                const int fm = half * 2 + fh;
                #pragma unroll
                for (int fn = 0; fn < 4; fn++)
                    o_acc[fm][fn] += cb[(((wr << 1) | fh) << 8) + (fn << 6) + lane];
                #pragma unroll
                for (int reg = 0; reg < 4; reg++) {
                    const int o = fm * 16 + g * 4 + reg;
                    const float sc = scale_s[o], sh = shift_s[o];
                    float* rowp = outp + (((size_t)b * COUT + o) * H_ + h_out) * W_ + w0 + i;
                    #pragma unroll
                    for (int fn = 0; fn < 4; fn++) {
                        const float v = o_acc[fm][fn][reg] * sc + sh;
                        rowp[fn * 16] = fmaxf(v, 0.f);
                    }
                }
            }
        }
        __syncthreads();                      // protect cb reuse for next half
    }
}

// ---------------------------------------------------------------------------
extern "C" void kernel_launch(void* const* d_in, const int* in_sizes, int n_in,
                              void* d_out, int out_size, void* d_ws, size_t ws_size,
                              hipStream_t stream) {
    const float* x     = (const float*)d_in[0];
    const float* kr    = (const float*)d_in[1];
    const float* mw    = (const float*)d_in[2];
    const float* mb    = (const float*)d_in[3];
    const float* gamma = (const float*)d_in[4];
    const float* beta  = (const float*)d_in[5];
    const float* mean  = (const float*)d_in[6];
    const float* var   = (const float*)d_in[7];

    float* outp  = (float*)d_out;
    float* masks = outp + (size_t)B_ * COUT * HW_;          // output #2 region

    unsigned short* xT  = (unsigned short*)d_ws;            // 16 MiB
    unsigned short* kT  = xT + (size_t)B_ * HW_ * CIN;      // +2.25 MiB
    unsigned short* mwT = kT + (size_t)B_ * RN_ * 9 * 4096; // +18 KiB

    hipLaunchKernelGGL(prep, dim3(1153), dim3(256), 0, stream, x, kr, mw, xT, kT, mwT);
    hipLaunchKernelGGL(main_conv, dim3(H_ / 4, 2, B_), dim3(512), 0, stream,
                       xT, kT, mwT, mb, gamma, beta, mean, var, outp, masks);
}

// Round 5
// 138.116 us; speedup vs baseline: 2.2808x; 2.2808x over previous
//
#include <hip/hip_runtime.h>
#include <hip/hip_bf16.h>

#define B_    8
#define CIN   64
#define COUT  64
#define RN_   4
#define H_    128
#define W_    128
#define HW_   (H_ * W_)
#define BN_EPS 1e-5f

typedef short v8s __attribute__((ext_vector_type(8)));
typedef float v4f __attribute__((ext_vector_type(4)));

__device__ __forceinline__ unsigned short f2bf(float f) {
    unsigned int u = __float_as_uint(f);
    u += 0x7FFFu + ((u >> 16) & 1u);       // round-to-nearest-even
    return (unsigned short)(u >> 16);
}

// ---------------------------------------------------------------------------
// prep: merged transpose kernels (one launch)
//   blocks [0,1024):    x fp32 [b][c][h][w] -> xT bf16 [b][h][w][c]
//   blocks [1024,1152): kernel fp32 -> kT bf16 in MFMA A-fragment order
//   block  1152:        mask weights fp32 [r][c][t] -> mwT bf16 in A-frag
//                       order (region replicated to rows r, r+4, r+8, r+12)
// ---------------------------------------------------------------------------
__global__ __launch_bounds__(256) void prep(const float* __restrict__ x,
                                            const float* __restrict__ kr,
                                            const float* __restrict__ mw,
                                            unsigned short* __restrict__ xT,
                                            unsigned short* __restrict__ kT,
                                            unsigned short* __restrict__ mwT) {
    __shared__ float sl[16 * 64 * 9];                 // 36 KB (union of both uses)
    if (blockIdx.x < 1024) {
        const int b = blockIdx.x >> 7, h = blockIdx.x & 127;
        const float* xp = x + (size_t)b * CIN * HW_ + (size_t)h * W_;
        for (int idx = threadIdx.x; idx < CIN * (W_ / 4); idx += 256) {
            const int c = idx >> 5, w4 = (idx & 31) << 2;   // float4 loads (G13)
            const float4 v = *(const float4*)(xp + (size_t)c * HW_ + w4);
            float* s = &sl[c * 129 + w4];                   // 129-pad: conflict-free col reads
            s[0] = v.x; s[1] = v.y; s[2] = v.z; s[3] = v.w;
        }
        __syncthreads();
        unsigned short* op = xT + ((size_t)b * H_ + h) * (W_ * CIN);
        for (int idx = threadIdx.x; idx < (W_ * CIN) / 8; idx += 256) {
            const int w = idx >> 3, c0 = (idx & 7) << 3;
            int4 v;
            v.x = f2bf(sl[(c0 + 0) * 129 + w]) | ((unsigned)f2bf(sl[(c0 + 1) * 129 + w]) << 16);
            v.y = f2bf(sl[(c0 + 2) * 129 + w]) | ((unsigned)f2bf(sl[(c0 + 3) * 129 + w]) << 16);
            v.z = f2bf(sl[(c0 + 4) * 129 + w]) | ((unsigned)f2bf(sl[(c0 + 5) * 129 + w]) << 16);
            v.w = f2bf(sl[(c0 + 6) * 129 + w]) | ((unsigned)f2bf(sl[(c0 + 7) * 129 + w]) << 16);
            *(int4*)(op + (w << 6) + c0) = v;
        }
    } else if (blockIdx.x < 1152) {
        const int bid = blockIdx.x - 1024;
        const int br = bid >> 2, oq = bid & 3;        // br = b*4+r; oq = 16-o chunk
        const float* src = kr + ((size_t)br * 64 + oq * 16) * (64 * 9);
        for (int idx = threadIdx.x; idx < 2304; idx += 256)
            *(float4*)&sl[idx << 2] = *(const float4*)&src[idx << 2];
        __syncthreads();
        unsigned short* dst = kT + (size_t)br * (9 * 4096);
        for (int idx = threadIdx.x; idx < 1152; idx += 256) {
            const int t = idx >> 7, rem = idx & 127, o16 = rem >> 3, c8 = (rem & 7) << 3;
            unsigned short s[8];
            #pragma unroll
            for (int j = 0; j < 8; j++)
                s[j] = f2bf(sl[(o16 * 64 + c8 + j) * 9 + t]);
            int4 v;
            v.x = s[0] | ((unsigned)s[1] << 16);
            v.y = s[2] | ((unsigned)s[3] << 16);
            v.z = s[4] | ((unsigned)s[5] << 16);
            v.w = s[6] | ((unsigned)s[7] << 16);
            // fragment order: o = oq*16+o16 -> fm=oq, i=o16 ; c = c8+j -> ks=c8>>5, g=(c8>>3)&3
            const int q  = oq * 2 + (c8 >> 5);        // frag index fm*2+ks
            const int gg = (c8 >> 3) & 3;             // g
            *(int4*)(dst + (size_t)t * 4096 + q * 512 + (gg * 16 + o16) * 8) = v;
        }
    } else {
        // mwT[tile=tap*2+ks][lane][8]: lane=(g<<4)|i, row i holds region i&3
        for (int idx = threadIdx.x; idx < 9 * 2 * 64 * 8; idx += 256) {
            const int tile = idx >> 9;                // tap*2+ks
            const int tap = tile >> 1, ks = tile & 1;
            const int lane = (idx >> 3) & 63, j = idx & 7;
            const int g = lane >> 4, r = lane & 3;    // region = i&3
            const int c = ks * 32 + g * 8 + j;
            mwT[idx] = f2bf(mw[(r * 64 + c) * 9 + tap]);
        }
    }
}

// ---------------------------------------------------------------------------
// fused: dynamic grouped conv + mask conv/softmax + region sum + BN + ReLU.
// Round 5 = round-2 structure (best: 47.7us) + two register-neutral changes:
//   (a) B-fragments software-pipelined one full tap ahead (2x 8-frag bufs)
//       -> the ~120cy ds_read latency (the measured 34%-MfmaUtil stall)
//       is covered by the 16 MFMAs of the previous tap.
//   (b) y_acc eliminated via scaled-Horner region fold: MFMAs accumulate
//       into o_acc; at region boundary o_acc *= m_r/m_{r+1}; epilogue *m_3.
//       Telescoping => weights identical to bf16-mask multiply (+-1e-7).
//       Masks clamped at 1e-12 pre-pack so denominators never vanish.
// Register estimate ~236 unified (was 252) at (256,2) -> no spill.
// ---------------------------------------------------------------------------
#define XS_W     66                      // 64 + 2 halo columns
#define XS_ROWS  6                       // 4 output rows + 2 halo rows
#define XS_ELEMS (XS_ROWS * XS_W * 64)   // 25344 shorts = 50.7 KB, swizzled

__global__ __launch_bounds__(256, 2) void main_conv(
        const unsigned short* __restrict__ xT,
        const unsigned short* __restrict__ kT,
        const unsigned short* __restrict__ mwT,
        const float* __restrict__ mb,
        const float* __restrict__ bn_gamma, const float* __restrict__ bn_beta,
        const float* __restrict__ bn_mean,  const float* __restrict__ bn_var,
        float* __restrict__ outp, float* __restrict__ masks_g) {
    __shared__ __align__(16) unsigned short xs[XS_ELEMS];
    __shared__ float scale_s[COUT];
    __shared__ float shift_s[COUT];

    const int tid = threadIdx.x;
    const int b  = blockIdx.z;
    const int w0 = blockIdx.y << 6;           // 0 or 64
    const int h0 = blockIdx.x << 2;           // 0..124
    const int lane = tid & 63, wv = tid >> 6; // wave wv owns output row h0+wv
    const int i = lane & 15, g = lane >> 4;
    const int h_out = h0 + wv;

    // ---- stage x halo tile, XOR-swizzled: slot' = slot ^ (rw&7) ----
    const unsigned short* xb = xT + (size_t)b * (HW_ * CIN);
    #pragma unroll
    for (int row = 0; row < XS_ROWS; row++) {
        const int h_in = h0 - 1 + row;
        const bool hok = (h_in >= 0) && (h_in < H_);
        for (int idx = tid; idx < XS_W * 8; idx += 256) {
            const int w = idx >> 3, c8 = (idx & 7) << 3;
            const int w_in = w0 - 1 + w;
            int4 v = make_int4(0, 0, 0, 0);
            if (hok && (w_in >= 0) && (w_in < W_))
                v = *(const int4*)(xb + ((h_in * W_ + w_in) << 6) + c8);
            const int rw = row * XS_W + w;
            *(int4*)(&xs[(rw << 6) + (((c8 >> 3) ^ (rw & 7)) << 3)]) = v;
        }
    }
    if (tid < COUT) {
        const float sc = bn_gamma[tid] * rsqrtf(bn_var[tid] + BN_EPS);
        scale_s[tid] = sc;
        shift_s[tid] = bn_beta[tid] - bn_mean[tid] * sc;
    }
    const float mb0 = mb[0], mb1 = mb[1], mb2 = mb[2], mb3 = mb[3];

    __syncthreads();                          // the ONLY barrier in this kernel

    // ---- logits pre-pass: 9 taps, A = mwT from global, softmax -> masks ----
    v4f lg_acc[4];
    #pragma unroll
    for (int fn = 0; fn < 4; fn++) lg_acc[fn] = (v4f){0.f, 0.f, 0.f, 0.f};
    for (int tap = 0; tap < 9; tap++) {
        const int rwb = (wv + tap / 3) * XS_W + i + tap % 3;
        const int base = (rwb << 6) + ((g ^ (rwb & 7)) << 3);
        #pragma unroll
        for (int ks = 0; ks < 2; ks++) {
            const v8s am = *(const v8s*)(mwT + (((tap * 2 + ks) << 9) + (lane << 3)));
            #pragma unroll
            for (int fn = 0; fn < 4; fn++) {
                const v8s bv = *(const v8s*)(&xs[(base + (fn << 10)) ^ (ks << 5)]);
                lg_acc[fn] = __builtin_amdgcn_mfma_f32_16x16x32_bf16(am, bv, lg_acc[fn], 0, 0, 0);
            }
        }
    }
    unsigned mk0[4], mk1[4];                  // bf16-packed clamped masks (r0|r1),(r2|r3)
    #pragma unroll
    for (int fn = 0; fn < 4; fn++) {
        const float l0 = lg_acc[fn][0] + mb0, l1 = lg_acc[fn][1] + mb1;
        const float l2 = lg_acc[fn][2] + mb2, l3 = lg_acc[fn][3] + mb3;
        const float mx = fmaxf(fmaxf(l0, l1), fmaxf(l2, l3));
        const float e0 = __expf(l0 - mx), e1 = __expf(l1 - mx);
        const float e2 = __expf(l2 - mx), e3 = __expf(l3 - mx);
        const float inv = 1.f / (e0 + e1 + e2 + e3);
        const float m0 = e0 * inv, m1 = e1 * inv, m2 = e2 * inv, m3 = e3 * inv;
        if (g == 0) {                         // lanes 0..15 hold valid rows 0..3
            float* mp = masks_g + ((size_t)b * RN_ * H_ + h_out) * W_ + w0 + fn * 16 + i;
            mp[0] = m0; mp[HW_] = m1; mp[2 * HW_] = m2; mp[3 * HW_] = m3;
        }
        mk0[fn] = f2bf(fmaxf(m0, 1e-12f)) | ((unsigned)f2bf(fmaxf(m1, 1e-12f)) << 16);
        mk1[fn] = f2bf(fmaxf(m2, 1e-12f)) | ((unsigned)f2bf(fmaxf(m3, 1e-12f)) << 16);
    }
    // broadcast masks from g==0 lanes to the whole wave (once, not per fold)
    #pragma unroll
    for (int fn = 0; fn < 4; fn++) {
        mk0[fn] = __shfl(mk0[fn], i);
        mk1[fn] = __shfl(mk1[fn], i);
    }
    auto mval = [&](int fn, int rr) -> float {
        const unsigned pk = (rr & 2) ? mk1[fn] : mk0[fn];
        return (rr & 1) ? __uint_as_float(pk & 0xffff0000u)
                        : __uint_as_float(pk << 16);
    };

    // ---- main loop: A dbuf from global, B dbuf from LDS (1 tap ahead) ----
    const unsigned short* kb = kT + (size_t)b * (36 * 4096) + (lane << 3);
    v4f o_acc[4][4];
    #pragma unroll
    for (int fm = 0; fm < 4; fm++)
        #pragma unroll
        for (int fn = 0; fn < 4; fn++)
            o_acc[fm][fn] = (v4f){0.f, 0.f, 0.f, 0.f};

    v8s aA[8], aB[8], b0[8], b1[8];
    auto lda = [&](v8s (&dst)[8], int t) {
        const unsigned short* kp = kb + ((size_t)t << 12);
        #pragma unroll
        for (int q = 0; q < 8; q++) dst[q] = *(const v8s*)(kp + (q << 9));
    };
    auto ldb = [&](v8s (&dst)[8], int t) {    // both ks halves of one tap
        const int rwb = (wv + t / 3) * XS_W + i + t % 3;
        const int base = (rwb << 6) + ((g ^ (rwb & 7)) << 3);
        #pragma unroll
        for (int fn = 0; fn < 4; fn++) {
            dst[fn]     = *(const v8s*)(&xs[base + (fn << 10)]);
            dst[4 + fn] = *(const v8s*)(&xs[(base + (fn << 10)) ^ 32]);
        }
    };

    lda(aA, 0); lda(aB, 1);
    ldb(b0, 0);

    int tap = 0, r = 0;
    auto step = [&](const v8s (&ac)[8], const v8s (&bc)[8], v8s (&bn)[8]) {
        const int ntap = (tap == 8) ? 0 : tap + 1;
        ldb(bn, ntap);                        // prefetch next tap's B-frags
        __builtin_amdgcn_s_setprio(1);
        #pragma unroll
        for (int ks = 0; ks < 2; ks++)
            #pragma unroll
            for (int fm = 0; fm < 4; fm++)
                #pragma unroll
                for (int fn = 0; fn < 4; fn++)
                    o_acc[fm][fn] = __builtin_amdgcn_mfma_f32_16x16x32_bf16(
                        ac[fm * 2 + ks], bc[ks * 4 + fn], o_acc[fm][fn], 0, 0, 0);
        __builtin_amdgcn_s_setprio(0);
        if (++tap == 9) {                     // region done: Horner fold
            tap = 0;
            if (r < 3) {
                #pragma unroll
                for (int fn = 0; fn < 4; fn++) {
                    const float ratio = mval(fn, r) / mval(fn, r + 1);
                    #pragma unroll
                    for (int fm = 0; fm < 4; fm++)
                        #pragma unroll
                        for (int c = 0; c < 4; c++)
                            o_acc[fm][fn][c] *= ratio;
                }
            }
            r++;
        }
    };

    for (int rt = 0; rt < 36; rt += 2) {
        step(aA, b0, b1);
        if (rt + 2 < 36) lda(aA, rt + 2);
        step(aB, b1, b0);
        if (rt + 3 < 36) lda(aB, rt + 3);
    }

    // ---- epilogue: *m3 (Horner final), BN + ReLU + store ----
    float mv3[4];
    #pragma unroll
    for (int fn = 0; fn < 4; fn++) mv3[fn] = mval(fn, 3);
    #pragma unroll
    for (int fm = 0; fm < 4; fm++) {
        #pragma unroll
        for (int reg = 0; reg < 4; reg++) {
            const int o = fm * 16 + g * 4 + reg;
            const float sc = scale_s[o], sh = shift_s[o];
            float* rowp = outp + (((size_t)b * COUT + o) * H_ + h_out) * W_ + w0 + i;
            #pragma unroll
            for (int fn = 0; fn < 4; fn++) {
                const float v = o_acc[fm][fn][reg] * mv3[fn] * sc + sh;
                rowp[fn * 16] = fmaxf(v, 0.f);
            }
        }
    }
}

// ---------------------------------------------------------------------------
extern "C" void kernel_launch(void* const* d_in, const int* in_sizes, int n_in,
                              void* d_out, int out_size, void* d_ws, size_t ws_size,
                              hipStream_t stream) {
    const float* x     = (const float*)d_in[0];
    const float* kr    = (const float*)d_in[1];
    const float* mw    = (const float*)d_in[2];
    const float* mb    = (const float*)d_in[3];
    const float* gamma = (const float*)d_in[4];
    const float* beta  = (const float*)d_in[5];
    const float* mean  = (const float*)d_in[6];
    const float* var   = (const float*)d_in[7];

    float* outp  = (float*)d_out;
    float* masks = outp + (size_t)B_ * COUT * HW_;          // output #2 region

    unsigned short* xT  = (unsigned short*)d_ws;            // 16 MiB
    unsigned short* kT  = xT + (size_t)B_ * HW_ * CIN;      // +2.25 MiB
    unsigned short* mwT = kT + (size_t)B_ * RN_ * 9 * 4096; // +18 KiB

    hipLaunchKernelGGL(prep, dim3(1153), dim3(256), 0, stream, x, kr, mw, xT, kT, mwT);
    hipLaunchKernelGGL(main_conv, dim3(H_ / 4, 2, B_), dim3(256), 0, stream,
                       xT, kT, mwT, mb, gamma, beta, mean, var, outp, masks);
}